// Round 5
// baseline (611.179 us; speedup 1.0000x reference)
//
#include <hip/hip_runtime.h>
#include <hip/hip_bf16.h>
#include <math.h>

// Problem constants
#define HID   64
#define VOCABN 64
#define INNER 24
#define SEQN  32
#define CAPN  8
#define NPOS  17
#define BATCHN 8192

typedef float f32x4 __attribute__((ext_vector_type(4)));

// ---------- cross-lane all-reduce, xor-butterfly pairing ----------
// Stages 1,2 via DPP quad_perm (VALU-rate); 4,8,16 via ds_swizzle; 32 via shfl.
// Pairing order is IDENTICAL to shfl_xor(1,2,4,8,16,32) => bit-exact vs round-4.
__device__ __forceinline__ float allred64(float x) {
  int y;
  y = __builtin_amdgcn_update_dpp(__float_as_int(x), __float_as_int(x),
                                  0xB1, 0xF, 0xF, false);   // quad_perm xor1
  x += __int_as_float(y);
  y = __builtin_amdgcn_update_dpp(__float_as_int(x), __float_as_int(x),
                                  0x4E, 0xF, 0xF, false);   // quad_perm xor2
  x += __int_as_float(y);
  x += __int_as_float(__builtin_amdgcn_ds_swizzle(__float_as_int(x), 0x101F)); // xor4
  x += __int_as_float(__builtin_amdgcn_ds_swizzle(__float_as_int(x), 0x201F)); // xor8
  x += __int_as_float(__builtin_amdgcn_ds_swizzle(__float_as_int(x), 0x401F)); // xor16
  x += __shfl_xor(x, 32);
  return x;
}

// ---------- Kernel 1: per-token encoder table (pure f32) ----------
// VERBATIM from round 4 (known-good bits).
__global__ __launch_bounds__(256) void build_table(
    const float* __restrict__ embed,    // [64][64]
    const float* __restrict__ ff_w1,    // [64][128]
    const float* __restrict__ ff_b1,    // [128]
    const float* __restrict__ ff_w2,    // [128][64]
    const float* __restrict__ ff_b2,    // [64]
    const float* __restrict__ ln_g,     // [64]
    const float* __restrict__ ln_b,     // [64]
    float* __restrict__ etab)           // [64][64]
{
  __shared__ float A1s[64][132];
  __shared__ float xs [64][68];
  const int t = threadIdx.x;

  {
    int n = t & 127, rg = t >> 7;
    for (int rr = 0; rr < 32; ++rr) {
      int r = rg * 32 + rr;
      float acc = ff_b1[n];
      for (int k = 0; k < 64; ++k)
        acc = fmaf(embed[r * 64 + k], ff_w1[k * 128 + n], acc);
      A1s[r][n] = fmaxf(acc, 0.f);
    }
  }
  __syncthreads();

  {
    int n = t & 63, rg = t >> 6;
    for (int rr = 0; rr < 16; ++rr) {
      int r = rg * 16 + rr;
      float acc = ff_b2[n];
      for (int k = 0; k < 128; ++k)
        acc = fmaf(A1s[r][k], ff_w2[k * 64 + n], acc);
      xs[r][n] = acc + embed[r * 64 + n];
    }
  }
  __syncthreads();

  {
    int r = t >> 2, c4 = t & 3;
    float s1 = 0.f;
    for (int j = 0; j < 16; ++j) s1 += xs[r][c4 + 4 * j];
    s1 += __shfl_xor(s1, 1);
    s1 += __shfl_xor(s1, 2);
    float mu = s1 * 0.015625f;
    float s2 = 0.f;
    for (int j = 0; j < 16; ++j) {
      float d = xs[r][c4 + 4 * j] - mu;
      s2 = fmaf(d, d, s2);
    }
    s2 += __shfl_xor(s2, 1);
    s2 += __shfl_xor(s2, 2);
    float var = s2 * 0.015625f;
    float rs  = rsqrtf(var + 1e-5f);
    for (int j = 0; j < 16; ++j) {
      int c = c4 + 4 * j;
      etab[r * 64 + c] = fmaf((xs[r][c] - mu) * rs, ln_g[c], ln_b[c]);
    }
  }
}

// ---------- Kernel 2: per-sample 8-step Adam + final projection ----------
// Fast transcendentals: v_sqrt_f32 (exact at 0) + v_rcp_f32 with one Newton
// refinement (~0.5 ulp) instead of IEEE libcall expansions (~27 instr saved
// per param-step; 392 param-steps/lane).
__device__ __forceinline__ void adam_upd(float& p, float& m, float& v, float g,
                                         float cm, float sb) {
  m = fmaf(0.9f, m, 0.1f * g);
  v = fmaf(0.999f, v, (0.001f * g) * g);
  float den = fmaf(__builtin_amdgcn_sqrtf(v), sb, 1e-8f);
  float r = __builtin_amdgcn_rcpf(den);
  r = r * fmaf(-den, r, 2.0f);          // Newton: err ~0.5 ulp
  p = fmaf(-(cm * m), r, p);
}

__global__ __launch_bounds__(256, 4) void adapt_kernel(
    const int* __restrict__ seqs,       // [BATCH][32]
    const float* __restrict__ etab,     // [64][64]
    const float* __restrict__ mlp_w1,   // [64][24]
    const float* __restrict__ mlp_b1,   // [24]
    const float* __restrict__ mlp_w2,   // [24][64]
    const float* __restrict__ mlp_b2,   // [64]
    const float* __restrict__ out_w,    // [64][64]
    const float* __restrict__ out_b,    // [64]
    float* __restrict__ out)            // [BATCH][64]
{
  __shared__ __align__(16) float tab[64 * 64];   // token -> enc row
  __shared__ __align__(16) float hqs[4][64];
  const int t = threadIdx.x;

  {
    const f32x4* src = (const f32x4*)etab;
    f32x4* dst = (f32x4*)tab;
    #pragma unroll
    for (int i = 0; i < 4; ++i) dst[t + 256 * i] = src[t + 256 * i];
  }
  __syncthreads();

  const int lane = t & 63;
  const int wv   = t >> 6;
  const int s    = blockIdx.x * 4 + wv;

  // token ids for positions 14..30 live in lanes 0..16
  int tok = 0;
  if (lane < NPOS) tok = seqs[s * SEQN + 14 + lane];

  // lane j owns: w1 row j, w2 column j, b2[j]; lanes<24 own b1[lane]
  float w1r[24], m1[24], v1[24], w2c[24], m2[24], v2[24];
  #pragma unroll
  for (int i = 0; i < 24; ++i) {
    w1r[i] = mlp_w1[lane * 24 + i];
    w2c[i] = mlp_w2[i * 64 + lane];
    m1[i] = 0.f; v1[i] = 0.f; m2[i] = 0.f; v2[i] = 0.f;
  }
  float b2o = mlp_b2[lane];
  float b1o = (lane < 24) ? mlp_b1[lane] : 0.f;
  float mb1 = 0.f, vb1 = 0.f, mb2 = 0.f, vb2 = 0.f;
  float pb1 = 1.f, pb2 = 1.f;

  #pragma unroll 1
  for (int st = 0; st < 8; ++st) {
    int tkk = __shfl(tok, 2 * st);
    int tvv = __shfl(tok, 2 * st + 1);
    float kj = tab[tkk * 64 + lane];
    float vj = tab[tvv * 64 + lane];

    // forward: z = W1^T k + b1  (64-lane reduce, replicated)
    float zp[24];
    #pragma unroll
    for (int i = 0; i < 24; ++i) zp[i] = kj * w1r[i];
    #pragma unroll
    for (int i = 0; i < 24; ++i) zp[i] += (lane == i) ? b1o : 0.f;
    #pragma unroll
    for (int i = 0; i < 24; ++i) zp[i] = allred64(zp[i]);

    float a[24];
    #pragma unroll
    for (int i = 0; i < 24; ++i) a[i] = fmaxf(zp[i], 0.f);

    float y = b2o;
    #pragma unroll
    for (int i = 0; i < 24; ++i) y = fmaf(a[i], w2c[i], y);
    float dy = (y - vj) * 0.03125f;   // 2/64

    // backward: da = W2 dy (reduce), dz = da * (z>0)
    float dz[24];
    #pragma unroll
    for (int i = 0; i < 24; ++i) dz[i] = w2c[i] * dy;
    #pragma unroll
    for (int i = 0; i < 24; ++i) dz[i] = allred64(dz[i]);
    #pragma unroll
    for (int i = 0; i < 24; ++i) dz[i] = (a[i] > 0.f) ? dz[i] : 0.f;

    // Adam step st+1
    pb1 *= 0.9f; pb2 *= 0.999f;
    float cm = 0.05f / (1.f - pb1);      // LR / bc1 (2 divs/step: keep exact)
    float sb = 1.f / sqrtf(1.f - pb2);   // 1/sqrt(bc2)
    #pragma unroll
    for (int i = 0; i < 24; ++i) adam_upd(w1r[i], m1[i], v1[i], kj * dz[i], cm, sb);
    #pragma unroll
    for (int i = 0; i < 24; ++i) adam_upd(w2c[i], m2[i], v2[i], a[i] * dy, cm, sb);
    adam_upd(b2o, mb2, vb2, dy, cm, sb);
    float gb1 = 0.f;
    #pragma unroll
    for (int i = 0; i < 24; ++i) gb1 = (lane == i) ? dz[i] : gb1;
    adam_upd(b1o, mb1, vb1, gb1, cm, sb);   // lanes>=24: g=0 -> no-op
  }

  // final forward with q (position 30 = lane 16's token)
  int tq = __shfl(tok, 16);
  float qj = tab[tq * 64 + lane];
  float zp[24];
  #pragma unroll
  for (int i = 0; i < 24; ++i) zp[i] = qj * w1r[i];
  #pragma unroll
  for (int i = 0; i < 24; ++i) zp[i] += (lane == i) ? b1o : 0.f;
  #pragma unroll
  for (int i = 0; i < 24; ++i) zp[i] = allred64(zp[i]);
  float hq = b2o;
  #pragma unroll
  for (int i = 0; i < 24; ++i) hq = fmaf(fmaxf(zp[i], 0.f), w2c[i], hq);

  hqs[wv][lane] = hq;
  __syncthreads();

  // out[s][c] = sum_j hq[j] * out_w[j][c] + out_b[c]   (lane = c)
  float acc = out_b[lane];
  const f32x4* hv = (const f32x4*)hqs[wv];
  #pragma unroll
  for (int j4 = 0; j4 < 16; ++j4) {
    f32x4 h4 = hv[j4];
    acc = fmaf(h4.x, out_w[(4 * j4 + 0) * 64 + lane], acc);
    acc = fmaf(h4.y, out_w[(4 * j4 + 1) * 64 + lane], acc);
    acc = fmaf(h4.z, out_w[(4 * j4 + 2) * 64 + lane], acc);
    acc = fmaf(h4.w, out_w[(4 * j4 + 3) * 64 + lane], acc);
  }
  out[(size_t)s * 64 + lane] = acc;
}

extern "C" void kernel_launch(void* const* d_in, const int* in_sizes, int n_in,
                              void* d_out, int out_size, void* d_ws, size_t ws_size,
                              hipStream_t stream) {
  const int*   seqs   = (const int*)d_in[0];
  const float* embed  = (const float*)d_in[1];
  const float* ff_w1  = (const float*)d_in[2];
  const float* ff_b1  = (const float*)d_in[3];
  const float* ff_w2  = (const float*)d_in[4];
  const float* ff_b2  = (const float*)d_in[5];
  const float* ln_g   = (const float*)d_in[6];
  const float* ln_b   = (const float*)d_in[7];
  const float* mlp_w1 = (const float*)d_in[8];
  const float* mlp_b1 = (const float*)d_in[9];
  const float* mlp_w2 = (const float*)d_in[10];
  const float* mlp_b2 = (const float*)d_in[11];
  const float* out_w  = (const float*)d_in[12];
  const float* out_b  = (const float*)d_in[13];

  float* etab = (float*)d_ws;   // 64*64 f32 = 16 KB

  build_table<<<1, 256, 0, stream>>>(
      embed, ff_w1, ff_b1, ff_w2, ff_b2, ln_g, ln_b, etab);
  adapt_kernel<<<BATCHN / 4, 256, 0, stream>>>(
      seqs, etab, mlp_w1, mlp_b1, mlp_w2, mlp_b2, out_w, out_b,
      (float*)d_out);
}

// Round 6
// 242.447 us; speedup vs baseline: 2.5209x; 2.5209x over previous
//
#include <hip/hip_runtime.h>
#include <hip/hip_bf16.h>
#include <math.h>

// Problem constants
#define HID   64
#define VOCABN 64
#define INNER 24
#define SEQN  32
#define CAPN  8
#define NPOS  17
#define BATCHN 8192

typedef float f32x4 __attribute__((ext_vector_type(4)));

// ---------- cross-lane all-reduce, xor-butterfly pairing ----------
// Stages 1,2 via DPP quad_perm (VALU-rate); 4,8,16 via ds_swizzle; 32 via shfl.
// Pairing identical to shfl_xor(1,2,4,8,16,32) => bit-exact vs rounds 4/5
// (both passed with absmax 0.0039).
__device__ __forceinline__ float allred64(float x) {
  int y;
  y = __builtin_amdgcn_update_dpp(__float_as_int(x), __float_as_int(x),
                                  0xB1, 0xF, 0xF, false);   // quad_perm xor1
  x += __int_as_float(y);
  y = __builtin_amdgcn_update_dpp(__float_as_int(x), __float_as_int(x),
                                  0x4E, 0xF, 0xF, false);   // quad_perm xor2
  x += __int_as_float(y);
  x += __int_as_float(__builtin_amdgcn_ds_swizzle(__float_as_int(x), 0x101F)); // xor4
  x += __int_as_float(__builtin_amdgcn_ds_swizzle(__float_as_int(x), 0x201F)); // xor8
  x += __int_as_float(__builtin_amdgcn_ds_swizzle(__float_as_int(x), 0x401F)); // xor16
  x += __shfl_xor(x, 32);
  return x;
}

// ---------- Kernel 1: per-token encoder table, one block per token ----------
// Bit-exact re-parallelization of the round-4 table builder: identical fma
// orders per column (phase1 k=0..63 from b1; phase2 k=0..127 from b2, +h),
// identical LN reduction tree (4 serial partials, xor1, xor2 — all-lane bits
// equal by IEEE add commutativity), identical rsqrtf.
__global__ __launch_bounds__(128) void build_table(
    const float* __restrict__ embed,    // [64][64]
    const float* __restrict__ ff_w1,    // [64][128]
    const float* __restrict__ ff_b1,    // [128]
    const float* __restrict__ ff_w2,    // [128][64]
    const float* __restrict__ ff_b2,    // [64]
    const float* __restrict__ ln_g,     // [64]
    const float* __restrict__ ln_b,     // [64]
    float* __restrict__ etab)           // [64][64]
{
  __shared__ float h[64];
  __shared__ float A1[128];
  __shared__ float xs[64];
  const int r = blockIdx.x;       // token id
  const int t = threadIdx.x;      // 0..127

  if (t < 64) h[t] = embed[r * 64 + t];
  __syncthreads();

  // phase 1: A1[n] = relu(b1[n] + sum_k h[k]*W1[k][n]), n = t
  {
    float acc = ff_b1[t];
    #pragma unroll 8
    for (int k = 0; k < 64; ++k)
      acc = fmaf(h[k], ff_w1[k * 128 + t], acc);
    A1[t] = fmaxf(acc, 0.f);
  }
  __syncthreads();

  // phase 2: x[n] = (b2[n] + sum_k A1[k]*W2[k][n]) + h[n], n = t (t<64)
  if (t < 64) {
    float acc = ff_b2[t];
    #pragma unroll 8
    for (int k = 0; k < 128; ++k)
      acc = fmaf(A1[k], ff_w2[k * 64 + t], acc);
    xs[t] = acc + h[t];
  }
  __syncthreads();

  // phase 3: LayerNorm (wave 0 only; same tree as round 4)
  if (t < 64) {
    // lanes 0..3 compute serial partials over stride-4 columns
    float s1 = 0.f;
    if (t < 4)
      for (int j = 0; j < 16; ++j) s1 += xs[t + 4 * j];
    s1 += __shfl_xor(s1, 1);
    s1 += __shfl_xor(s1, 2);
    s1 = __shfl(s1, 0);
    float mu = s1 * 0.015625f;

    float s2 = 0.f;
    if (t < 4)
      for (int j = 0; j < 16; ++j) {
        float d = xs[t + 4 * j] - mu;
        s2 = fmaf(d, d, s2);
      }
    s2 += __shfl_xor(s2, 1);
    s2 += __shfl_xor(s2, 2);
    s2 = __shfl(s2, 0);
    float var = s2 * 0.015625f;
    float rs  = rsqrtf(var + 1e-5f);

    etab[r * 64 + t] = fmaf((xs[t] - mu) * rs, ln_g[t], ln_b[t]);
  }
}

// ---------- Kernel 2: per-sample 8-step Adam + final projection ----------
// Fast transcendentals: v_sqrt_f32 (exact at 0) + v_rcp_f32 with one Newton
// refinement (~0.5 ulp). Verified passing in round 5 (absmax 0.0039).
__device__ __forceinline__ void adam_upd(float& p, float& m, float& v, float g,
                                         float cm, float sb) {
  m = fmaf(0.9f, m, 0.1f * g);
  v = fmaf(0.999f, v, (0.001f * g) * g);
  float den = fmaf(__builtin_amdgcn_sqrtf(v), sb, 1e-8f);
  float r = __builtin_amdgcn_rcpf(den);
  r = r * fmaf(-den, r, 2.0f);          // Newton: err ~0.5 ulp
  p = fmaf(-(cm * m), r, p);
}

// __launch_bounds__(256,2): round 5's (256,4) capped VGPR at 64 and spilled
// the whole Adam state to scratch (2.5 GB HBM traffic, 63% of peak BW).
// (256,2) gives 124 VGPR + AGPR headroom (gfx950 unified file) — zero spill.
__global__ __launch_bounds__(256, 2) void adapt_kernel(
    const int* __restrict__ seqs,       // [BATCH][32]
    const float* __restrict__ etab,     // [64][64]
    const float* __restrict__ mlp_w1,   // [64][24]
    const float* __restrict__ mlp_b1,   // [24]
    const float* __restrict__ mlp_w2,   // [24][64]
    const float* __restrict__ mlp_b2,   // [64]
    const float* __restrict__ out_w,    // [64][64]
    const float* __restrict__ out_b,    // [64]
    float* __restrict__ out)            // [BATCH][64]
{
  __shared__ __align__(16) float tab[64 * 64];   // token -> enc row
  __shared__ __align__(16) float hqs[4][64];
  const int t = threadIdx.x;

  {
    const f32x4* src = (const f32x4*)etab;
    f32x4* dst = (f32x4*)tab;
    #pragma unroll
    for (int i = 0; i < 4; ++i) dst[t + 256 * i] = src[t + 256 * i];
  }
  __syncthreads();

  const int lane = t & 63;
  const int wv   = t >> 6;
  const int s    = blockIdx.x * 4 + wv;

  // token ids for positions 14..30 live in lanes 0..16
  int tok = 0;
  if (lane < NPOS) tok = seqs[s * SEQN + 14 + lane];

  // lane j owns: w1 row j, w2 column j, b2[j]; lanes<24 own b1[lane]
  float w1r[24], m1[24], v1[24], w2c[24], m2[24], v2[24];
  #pragma unroll
  for (int i = 0; i < 24; ++i) {
    w1r[i] = mlp_w1[lane * 24 + i];
    w2c[i] = mlp_w2[i * 64 + lane];
    m1[i] = 0.f; v1[i] = 0.f; m2[i] = 0.f; v2[i] = 0.f;
  }
  float b2o = mlp_b2[lane];
  float b1o = (lane < 24) ? mlp_b1[lane] : 0.f;
  float mb1 = 0.f, vb1 = 0.f, mb2 = 0.f, vb2 = 0.f;
  float pb1 = 1.f, pb2 = 1.f;

  #pragma unroll 1
  for (int st = 0; st < 8; ++st) {
    int tkk = __shfl(tok, 2 * st);
    int tvv = __shfl(tok, 2 * st + 1);
    float kj = tab[tkk * 64 + lane];
    float vj = tab[tvv * 64 + lane];

    // forward: z = W1^T k + b1  (64-lane reduce, replicated)
    float zp[24];
    #pragma unroll
    for (int i = 0; i < 24; ++i) zp[i] = kj * w1r[i];
    #pragma unroll
    for (int i = 0; i < 24; ++i) zp[i] += (lane == i) ? b1o : 0.f;
    #pragma unroll
    for (int i = 0; i < 24; ++i) zp[i] = allred64(zp[i]);

    float a[24];
    #pragma unroll
    for (int i = 0; i < 24; ++i) a[i] = fmaxf(zp[i], 0.f);

    float y = b2o;
    #pragma unroll
    for (int i = 0; i < 24; ++i) y = fmaf(a[i], w2c[i], y);
    float dy = (y - vj) * 0.03125f;   // 2/64

    // backward: da = W2 dy (reduce), dz = da * (z>0)
    float dz[24];
    #pragma unroll
    for (int i = 0; i < 24; ++i) dz[i] = w2c[i] * dy;
    #pragma unroll
    for (int i = 0; i < 24; ++i) dz[i] = allred64(dz[i]);
    #pragma unroll
    for (int i = 0; i < 24; ++i) dz[i] = (a[i] > 0.f) ? dz[i] : 0.f;

    // Adam step st+1
    pb1 *= 0.9f; pb2 *= 0.999f;
    float cm = 0.05f / (1.f - pb1);      // once per step: keep exact
    float sb = 1.f / sqrtf(1.f - pb2);
    #pragma unroll
    for (int i = 0; i < 24; ++i) adam_upd(w1r[i], m1[i], v1[i], kj * dz[i], cm, sb);
    #pragma unroll
    for (int i = 0; i < 24; ++i) adam_upd(w2c[i], m2[i], v2[i], a[i] * dy, cm, sb);
    adam_upd(b2o, mb2, vb2, dy, cm, sb);
    float gb1 = 0.f;
    #pragma unroll
    for (int i = 0; i < 24; ++i) gb1 = (lane == i) ? dz[i] : gb1;
    adam_upd(b1o, mb1, vb1, gb1, cm, sb);   // lanes>=24: g=0 -> no-op
  }

  // final forward with q (position 30 = lane 16's token)
  int tq = __shfl(tok, 16);
  float qj = tab[tq * 64 + lane];
  float zp[24];
  #pragma unroll
  for (int i = 0; i < 24; ++i) zp[i] = qj * w1r[i];
  #pragma unroll
  for (int i = 0; i < 24; ++i) zp[i] += (lane == i) ? b1o : 0.f;
  #pragma unroll
  for (int i = 0; i < 24; ++i) zp[i] = allred64(zp[i]);
  float hq = b2o;
  #pragma unroll
  for (int i = 0; i < 24; ++i) hq = fmaf(fmaxf(zp[i], 0.f), w2c[i], hq);

  hqs[wv][lane] = hq;
  __syncthreads();

  // out[s][c] = sum_j hq[j] * out_w[j][c] + out_b[c]   (lane = c)
  float acc = out_b[lane];
  const f32x4* hv = (const f32x4*)hqs[wv];
  #pragma unroll
  for (int j4 = 0; j4 < 16; ++j4) {
    f32x4 h4 = hv[j4];
    acc = fmaf(h4.x, out_w[(4 * j4 + 0) * 64 + lane], acc);
    acc = fmaf(h4.y, out_w[(4 * j4 + 1) * 64 + lane], acc);
    acc = fmaf(h4.z, out_w[(4 * j4 + 2) * 64 + lane], acc);
    acc = fmaf(h4.w, out_w[(4 * j4 + 3) * 64 + lane], acc);
  }
  out[(size_t)s * 64 + lane] = acc;
}

extern "C" void kernel_launch(void* const* d_in, const int* in_sizes, int n_in,
                              void* d_out, int out_size, void* d_ws, size_t ws_size,
                              hipStream_t stream) {
  const int*   seqs   = (const int*)d_in[0];
  const float* embed  = (const float*)d_in[1];
  const float* ff_w1  = (const float*)d_in[2];
  const float* ff_b1  = (const float*)d_in[3];
  const float* ff_w2  = (const float*)d_in[4];
  const float* ff_b2  = (const float*)d_in[5];
  const float* ln_g   = (const float*)d_in[6];
  const float* ln_b   = (const float*)d_in[7];
  const float* mlp_w1 = (const float*)d_in[8];
  const float* mlp_b1 = (const float*)d_in[9];
  const float* mlp_w2 = (const float*)d_in[10];
  const float* mlp_b2 = (const float*)d_in[11];
  const float* out_w  = (const float*)d_in[12];
  const float* out_b  = (const float*)d_in[13];

  float* etab = (float*)d_ws;   // 64*64 f32 = 16 KB

  build_table<<<64, 128, 0, stream>>>(
      embed, ff_w1, ff_b1, ff_w2, ff_b2, ln_g, ln_b, etab);
  adapt_kernel<<<BATCHN / 4, 256, 0, stream>>>(
      seqs, etab, mlp_w1, mlp_b1, mlp_w2, mlp_b2, out_w, out_b,
      (float*)d_out);
}

// Round 7
// 235.348 us; speedup vs baseline: 2.5969x; 1.0302x over previous
//
#include <hip/hip_runtime.h>
#include <hip/hip_bf16.h>
#include <math.h>

// Problem constants
#define HID   64
#define VOCABN 64
#define INNER 24
#define SEQN  32
#define CAPN  8
#define NPOS  17
#define BATCHN 8192

typedef float f32x4 __attribute__((ext_vector_type(4)));
typedef float f32x2 __attribute__((ext_vector_type(2)));

#if __has_builtin(__builtin_elementwise_fma)
#define FMA2(a,b,c) __builtin_elementwise_fma((f32x2)(a),(f32x2)(b),(f32x2)(c))
#else
#define FMA2(a,b,c) ((a)*(b)+(c))
#endif
#if __has_builtin(__builtin_elementwise_max)
#define MAX2(a,b) __builtin_elementwise_max((f32x2)(a),(f32x2)(b))
#else
__device__ __forceinline__ f32x2 MAX2(f32x2 a, f32x2 b){ f32x2 r; r.x=fmaxf(a.x,b.x); r.y=fmaxf(a.y,b.y); return r; }
#endif

// ---------- cross-lane helpers ----------
__device__ __forceinline__ float dppx(float x, int ctrl_b1) {
  // quad_perm via update_dpp, same encoding as rounds 5/6 (bit-exact lineage)
  int y = ctrl_b1
    ? __builtin_amdgcn_update_dpp(__float_as_int(x), __float_as_int(x), 0xB1, 0xF, 0xF, false)
    : __builtin_amdgcn_update_dpp(__float_as_int(x), __float_as_int(x), 0x4E, 0xF, 0xF, false);
  return __int_as_float(y);
}

// packed all-reduce: each 32-bit half goes through the IDENTICAL xor-butterfly
// (1,2 via DPP; 4,8,16 via ds_swizzle; 32 via shfl) as rounds 4/5/6 => bit-exact.
__device__ __forceinline__ f32x2 allred64v(f32x2 x) {
  f32x2 t;
  t.x = dppx(x.x, 1); t.y = dppx(x.y, 1); x += t;                       // xor1
  t.x = dppx(x.x, 0); t.y = dppx(x.y, 0); x += t;                       // xor2
  t.x = __int_as_float(__builtin_amdgcn_ds_swizzle(__float_as_int(x.x), 0x101F));
  t.y = __int_as_float(__builtin_amdgcn_ds_swizzle(__float_as_int(x.y), 0x101F));
  x += t;                                                               // xor4
  t.x = __int_as_float(__builtin_amdgcn_ds_swizzle(__float_as_int(x.x), 0x201F));
  t.y = __int_as_float(__builtin_amdgcn_ds_swizzle(__float_as_int(x.y), 0x201F));
  x += t;                                                               // xor8
  t.x = __int_as_float(__builtin_amdgcn_ds_swizzle(__float_as_int(x.x), 0x401F));
  t.y = __int_as_float(__builtin_amdgcn_ds_swizzle(__float_as_int(x.y), 0x401F));
  x += t;                                                               // xor16
  t.x = __shfl_xor(x.x, 32); t.y = __shfl_xor(x.y, 32); x += t;         // xor32
  return x;
}

// ---------- Kernel 1: per-token encoder table (verbatim round 6, passing) ----------
__global__ __launch_bounds__(128) void build_table(
    const float* __restrict__ embed,    // [64][64]
    const float* __restrict__ ff_w1,    // [64][128]
    const float* __restrict__ ff_b1,    // [128]
    const float* __restrict__ ff_w2,    // [128][64]
    const float* __restrict__ ff_b2,    // [64]
    const float* __restrict__ ln_g,     // [64]
    const float* __restrict__ ln_b,     // [64]
    float* __restrict__ etab)           // [64][64]
{
  __shared__ float h[64];
  __shared__ float A1[128];
  __shared__ float xs[64];
  const int r = blockIdx.x;
  const int t = threadIdx.x;

  if (t < 64) h[t] = embed[r * 64 + t];
  __syncthreads();

  {
    float acc = ff_b1[t];
    #pragma unroll 8
    for (int k = 0; k < 64; ++k)
      acc = fmaf(h[k], ff_w1[k * 128 + t], acc);
    A1[t] = fmaxf(acc, 0.f);
  }
  __syncthreads();

  if (t < 64) {
    float acc = ff_b2[t];
    #pragma unroll 8
    for (int k = 0; k < 128; ++k)
      acc = fmaf(A1[k], ff_w2[k * 64 + t], acc);
    xs[t] = acc + h[t];
  }
  __syncthreads();

  if (t < 64) {
    float s1 = 0.f;
    if (t < 4)
      for (int j = 0; j < 16; ++j) s1 += xs[t + 4 * j];
    s1 += __shfl_xor(s1, 1);
    s1 += __shfl_xor(s1, 2);
    s1 = __shfl(s1, 0);
    float mu = s1 * 0.015625f;

    float s2 = 0.f;
    if (t < 4)
      for (int j = 0; j < 16; ++j) {
        float d = xs[t + 4 * j] - mu;
        s2 = fmaf(d, d, s2);
      }
    s2 += __shfl_xor(s2, 1);
    s2 += __shfl_xor(s2, 2);
    s2 = __shfl(s2, 0);
    float var = s2 * 0.015625f;
    float rs  = rsqrtf(var + 1e-5f);

    etab[r * 64 + t] = fmaf((xs[t] - mu) * rs, ln_g[t], ln_b[t]);
  }
}

// ---------- Kernel 2: per-sample 8-step Adam, f32x2-packed over INNER ----------
// Packed Adam: per-half op sequence identical to round 6's scalar adam_upd
// (v_pk_* rounds each half exactly like the scalar op) => bit-exact.
__device__ __forceinline__ void adam_upd2(f32x2& p, f32x2& m, f32x2& v, f32x2 g,
                                          float cm, float sb) {
  m = FMA2(0.9f, m, 0.1f * g);
  v = FMA2(0.999f, v, (0.001f * g) * g);
  f32x2 sq;
  sq.x = __builtin_amdgcn_sqrtf(v.x);
  sq.y = __builtin_amdgcn_sqrtf(v.y);
  f32x2 den = FMA2(sq, sb, 1e-8f);
  f32x2 r;
  r.x = __builtin_amdgcn_rcpf(den.x);
  r.y = __builtin_amdgcn_rcpf(den.y);
  r = r * FMA2(-den, r, 2.0f);          // Newton: err ~0.5 ulp per half
  p = FMA2(-(cm * m), r, p);
}

// (256,2): 124-128 VGPR + AGPR headroom, zero spill (round 6 verified).
__global__ __launch_bounds__(256, 2) void adapt_kernel(
    const int* __restrict__ seqs,       // [BATCH][32]
    const float* __restrict__ etab,     // [64][64]
    const float* __restrict__ mlp_w1,   // [64][24]
    const float* __restrict__ mlp_b1,   // [24]
    const float* __restrict__ mlp_w2,   // [24][64]
    const float* __restrict__ mlp_b2,   // [64]
    const float* __restrict__ out_w,    // [64][64]
    const float* __restrict__ out_b,    // [64]
    float* __restrict__ out)            // [BATCH][64]
{
  __shared__ __align__(16) float tab[64 * 64];   // token -> enc row
  __shared__ __align__(16) float hqs[4][64];
  const int t = threadIdx.x;

  {
    const f32x4* src = (const f32x4*)etab;
    f32x4* dst = (f32x4*)tab;
    #pragma unroll
    for (int i = 0; i < 4; ++i) dst[t + 256 * i] = src[t + 256 * i];
  }
  __syncthreads();

  const int lane = t & 63;
  const int wv   = t >> 6;
  const int s    = blockIdx.x * 4 + wv;

  int tok = 0;
  if (lane < NPOS) tok = seqs[s * SEQN + 14 + lane];

  // lane j owns: w1 row j, w2 column j, b2[j]; lanes<24 own b1[lane]
  f32x2 w1r[12], m1[12], v1[12], w2c[12], m2[12], v2[12];
  #pragma unroll
  for (int i = 0; i < 12; ++i) {
    w1r[i] = *(const f32x2*)&mlp_w1[lane * 24 + 2 * i];   // 8B-aligned
    w2c[i].x = mlp_w2[(2 * i) * 64 + lane];
    w2c[i].y = mlp_w2[(2 * i + 1) * 64 + lane];
    m1[i] = 0.f; v1[i] = 0.f; m2[i] = 0.f; v2[i] = 0.f;
  }
  // bias pair: {b1[lane] (lanes<24), b2[lane]}
  f32x2 pb; pb.x = (lane < 24) ? mlp_b1[lane] : 0.f; pb.y = mlp_b2[lane];
  f32x2 mb = {0.f, 0.f}, vb = {0.f, 0.f};
  float pb1 = 1.f, pb2 = 1.f;

  #pragma unroll 1
  for (int st = 0; st < 8; ++st) {
    int tkk = __shfl(tok, 2 * st);
    int tvv = __shfl(tok, 2 * st + 1);
    float kj = tab[tkk * 64 + lane];
    float vj = tab[tvv * 64 + lane];

    // forward: z = W1^T k + b1  (mul, then lane-selected bias add, then
    // xor-butterfly — identical op order per half as round 6)
    f32x2 zp[12];
    #pragma unroll
    for (int i = 0; i < 12; ++i) zp[i] = kj * w1r[i];
    #pragma unroll
    for (int i = 0; i < 12; ++i) {
      zp[i].x += (lane == 2 * i)     ? pb.x : 0.f;
      zp[i].y += (lane == 2 * i + 1) ? pb.x : 0.f;
    }
    #pragma unroll
    for (int i = 0; i < 12; ++i) zp[i] = allred64v(zp[i]);

    f32x2 a[12];
    #pragma unroll
    for (int i = 0; i < 12; ++i) a[i] = MAX2(zp[i], 0.f);

    // y: serial scalar accumulation, same order as round 6
    float y = pb.y;
    #pragma unroll
    for (int i = 0; i < 12; ++i) {
      y = fmaf(a[i].x, w2c[i].x, y);
      y = fmaf(a[i].y, w2c[i].y, y);
    }
    float dy = (y - vj) * 0.03125f;   // 2/64

    // backward: dz = allred(w2c*dy) gated by (a>0)
    f32x2 dz[12];
    #pragma unroll
    for (int i = 0; i < 12; ++i) dz[i] = w2c[i] * dy;
    #pragma unroll
    for (int i = 0; i < 12; ++i) dz[i] = allred64v(dz[i]);
    #pragma unroll
    for (int i = 0; i < 12; ++i) {
      dz[i].x = (a[i].x > 0.f) ? dz[i].x : 0.f;
      dz[i].y = (a[i].y > 0.f) ? dz[i].y : 0.f;
    }

    // Adam step st+1 (cm/sb exact, as round 6)
    pb1 *= 0.9f; pb2 *= 0.999f;
    float cm = 0.05f / (1.f - pb1);
    float sb = 1.f / sqrtf(1.f - pb2);
    #pragma unroll
    for (int i = 0; i < 12; ++i) adam_upd2(w1r[i], m1[i], v1[i], kj * dz[i], cm, sb);
    #pragma unroll
    for (int i = 0; i < 12; ++i) adam_upd2(w2c[i], m2[i], v2[i], a[i] * dy, cm, sb);
    float gb1 = 0.f;
    #pragma unroll
    for (int i = 0; i < 12; ++i) {
      gb1 = (lane == 2 * i)     ? dz[i].x : gb1;
      gb1 = (lane == 2 * i + 1) ? dz[i].y : gb1;
    }
    f32x2 gb; gb.x = gb1; gb.y = dy;
    adam_upd2(pb, mb, vb, gb, cm, sb);   // lanes>=24: gb.x=0 -> no-op on b1 half
  }

  // final forward with q (position 30 = lane 16's token)
  int tq = __shfl(tok, 16);
  float qj = tab[tq * 64 + lane];
  f32x2 zp[12];
  #pragma unroll
  for (int i = 0; i < 12; ++i) zp[i] = qj * w1r[i];
  #pragma unroll
  for (int i = 0; i < 12; ++i) {
    zp[i].x += (lane == 2 * i)     ? pb.x : 0.f;
    zp[i].y += (lane == 2 * i + 1) ? pb.x : 0.f;
  }
  #pragma unroll
  for (int i = 0; i < 12; ++i) zp[i] = allred64v(zp[i]);
  float hq = pb.y;
  #pragma unroll
  for (int i = 0; i < 12; ++i) {
    hq = fmaf(fmaxf(zp[i].x, 0.f), w2c[i].x, hq);
    hq = fmaf(fmaxf(zp[i].y, 0.f), w2c[i].y, hq);
  }

  hqs[wv][lane] = hq;
  __syncthreads();

  // out[s][c] = sum_j hq[j] * out_w[j][c] + out_b[c]   (lane = c)
  float acc = out_b[lane];
  const f32x4* hv = (const f32x4*)hqs[wv];
  #pragma unroll
  for (int j4 = 0; j4 < 16; ++j4) {
    f32x4 h4 = hv[j4];
    acc = fmaf(h4.x, out_w[(4 * j4 + 0) * 64 + lane], acc);
    acc = fmaf(h4.y, out_w[(4 * j4 + 1) * 64 + lane], acc);
    acc = fmaf(h4.z, out_w[(4 * j4 + 2) * 64 + lane], acc);
    acc = fmaf(h4.w, out_w[(4 * j4 + 3) * 64 + lane], acc);
  }
  out[(size_t)s * 64 + lane] = acc;
}

extern "C" void kernel_launch(void* const* d_in, const int* in_sizes, int n_in,
                              void* d_out, int out_size, void* d_ws, size_t ws_size,
                              hipStream_t stream) {
  const int*   seqs   = (const int*)d_in[0];
  const float* embed  = (const float*)d_in[1];
  const float* ff_w1  = (const float*)d_in[2];
  const float* ff_b1  = (const float*)d_in[3];
  const float* ff_w2  = (const float*)d_in[4];
  const float* ff_b2  = (const float*)d_in[5];
  const float* ln_g   = (const float*)d_in[6];
  const float* ln_b   = (const float*)d_in[7];
  const float* mlp_w1 = (const float*)d_in[8];
  const float* mlp_b1 = (const float*)d_in[9];
  const float* mlp_w2 = (const float*)d_in[10];
  const float* mlp_b2 = (const float*)d_in[11];
  const float* out_w  = (const float*)d_in[12];
  const float* out_b  = (const float*)d_in[13];

  float* etab = (float*)d_ws;   // 64*64 f32 = 16 KB

  build_table<<<64, 128, 0, stream>>>(
      embed, ff_w1, ff_b1, ff_w2, ff_b2, ln_g, ln_b, etab);
  adapt_kernel<<<BATCHN / 4, 256, 0, stream>>>(
      seqs, etab, mlp_w1, mlp_b1, mlp_w2, mlp_b2, out_w, out_b,
      (float*)d_out);
}

// Round 8
// 230.152 us; speedup vs baseline: 2.6555x; 1.0226x over previous
//
#include <hip/hip_runtime.h>
#include <hip/hip_bf16.h>
#include <math.h>

// Problem constants
#define HID   64
#define VOCABN 64
#define INNER 24
#define SEQN  32
#define CAPN  8
#define NPOS  17
#define BATCHN 8192

typedef float f32x4 __attribute__((ext_vector_type(4)));

// ---------- cross-lane all-reduce, xor-butterfly (bit-exact lineage r4-r7) ----------
__device__ __forceinline__ float allred64(float x) {
  int y;
  y = __builtin_amdgcn_update_dpp(__float_as_int(x), __float_as_int(x),
                                  0xB1, 0xF, 0xF, false);   // quad_perm xor1
  x += __int_as_float(y);
  y = __builtin_amdgcn_update_dpp(__float_as_int(x), __float_as_int(x),
                                  0x4E, 0xF, 0xF, false);   // quad_perm xor2
  x += __int_as_float(y);
  x += __int_as_float(__builtin_amdgcn_ds_swizzle(__float_as_int(x), 0x101F)); // xor4
  x += __int_as_float(__builtin_amdgcn_ds_swizzle(__float_as_int(x), 0x201F)); // xor8
  x += __int_as_float(__builtin_amdgcn_ds_swizzle(__float_as_int(x), 0x401F)); // xor16
  x += __shfl_xor(x, 32);
  return x;
}

// ---------- Kernel 1: per-token encoder table (verbatim round 6, passing) ----------
__global__ __launch_bounds__(128) void build_table(
    const float* __restrict__ embed,    // [64][64]
    const float* __restrict__ ff_w1,    // [64][128]
    const float* __restrict__ ff_b1,    // [128]
    const float* __restrict__ ff_w2,    // [128][64]
    const float* __restrict__ ff_b2,    // [64]
    const float* __restrict__ ln_g,     // [64]
    const float* __restrict__ ln_b,     // [64]
    float* __restrict__ etab)           // [64][64]
{
  __shared__ float h[64];
  __shared__ float A1[128];
  __shared__ float xs[64];
  const int r = blockIdx.x;
  const int t = threadIdx.x;

  if (t < 64) h[t] = embed[r * 64 + t];
  __syncthreads();

  {
    float acc = ff_b1[t];
    #pragma unroll 8
    for (int k = 0; k < 64; ++k)
      acc = fmaf(h[k], ff_w1[k * 128 + t], acc);
    A1[t] = fmaxf(acc, 0.f);
  }
  __syncthreads();

  if (t < 64) {
    float acc = ff_b2[t];
    #pragma unroll 8
    for (int k = 0; k < 128; ++k)
      acc = fmaf(A1[k], ff_w2[k * 64 + t], acc);
    xs[t] = acc + h[t];
  }
  __syncthreads();

  if (t < 64) {
    float s1 = 0.f;
    if (t < 4)
      for (int j = 0; j < 16; ++j) s1 += xs[t + 4 * j];
    s1 += __shfl_xor(s1, 1);
    s1 += __shfl_xor(s1, 2);
    s1 = __shfl(s1, 0);
    float mu = s1 * 0.015625f;

    float s2 = 0.f;
    if (t < 4)
      for (int j = 0; j < 16; ++j) {
        float d = xs[t + 4 * j] - mu;
        s2 = fmaf(d, d, s2);
      }
    s2 += __shfl_xor(s2, 1);
    s2 += __shfl_xor(s2, 2);
    s2 = __shfl(s2, 0);
    float var = s2 * 0.015625f;
    float rs  = rsqrtf(var + 1e-5f);

    etab[r * 64 + t] = fmaf((xs[t] - mu) * rs, ln_g[t], ln_b[t]);
  }
}

// ---------- Kernel 2: 2-wave-per-sample 8-step Adam ----------
// wave w of a 128-thread block owns inner dims [12w, 12w+12).
// Per-lane state halves vs r7 (72+misc regs) -> 3 waves/SIMD instead of 2.
// No Newton on rcp (1-ulp raw v_rcp; perturbation ~1e-7 rel, threshold 18x away).
__device__ __forceinline__ void adam_upd(float& p, float& m, float& v, float g,
                                         float cm, float sb) {
  m = fmaf(0.9f, m, 0.1f * g);
  v = fmaf(0.999f, v, (0.001f * g) * g);
  float den = fmaf(__builtin_amdgcn_sqrtf(v), sb, 1e-8f);
  p = fmaf(-(cm * m), __builtin_amdgcn_rcpf(den), p);
}

__global__ __launch_bounds__(128, 3) void adapt_kernel(
    const int* __restrict__ seqs,       // [BATCH][32]
    const float* __restrict__ etab,     // [64][64]
    const float* __restrict__ mlp_w1,   // [64][24]
    const float* __restrict__ mlp_b1,   // [24]
    const float* __restrict__ mlp_w2,   // [24][64]
    const float* __restrict__ mlp_b2,   // [64]
    const float* __restrict__ out_w,    // [64][64]
    const float* __restrict__ out_b,    // [64]
    float* __restrict__ out)            // [BATCH][64]
{
  __shared__ float ybuf[2][2][64];     // [step parity][wave][col]
  __shared__ float hqv[64];
  const int t    = threadIdx.x;        // 0..127
  const int lane = t & 63;
  const int w    = t >> 6;             // 0 or 1
  const int s    = blockIdx.x;
  const int i0   = 12 * w;

  int tok = (lane < NPOS) ? seqs[s * SEQN + 14 + lane] : 0;

  // state: lane j owns w1[j][i0..i0+12), w2[i0..i0+12)[j];
  // lanes<12 own b1[i0+lane]; wave0 owns b2[lane].
  float w1r[12], m1[12], v1[12], w2c[12], m2[12], v2[12];
  #pragma unroll
  for (int i = 0; i < 12; ++i) {
    w1r[i] = mlp_w1[lane * 24 + i0 + i];
    w2c[i] = mlp_w2[(i0 + i) * 64 + lane];
    m1[i] = 0.f; v1[i] = 0.f; m2[i] = 0.f; v2[i] = 0.f;
  }
  float b1o = (lane < 12) ? mlp_b1[i0 + lane] : 0.f;
  float b2o = (w == 0) ? mlp_b2[lane] : 0.f;
  float mb1 = 0.f, vb1 = 0.f, mb2 = 0.f, vb2 = 0.f;
  float pb1 = 1.f, pb2 = 1.f;

  // first k,v rows (direct from L2-resident etab)
  int tk = __shfl(tok, 0), tv = __shfl(tok, 1);
  float kj = etab[tk * 64 + lane];
  float vj = etab[tv * 64 + lane];

  #pragma unroll 1
  for (int st = 0; st < 8; ++st) {
    // forward: z_i (i in wave's half) = allred(k_j * w1[j][i]) + b1
    float zp[12];
    #pragma unroll
    for (int i = 0; i < 12; ++i) zp[i] = kj * w1r[i];
    #pragma unroll
    for (int i = 0; i < 12; ++i) zp[i] += (lane == i) ? b1o : 0.f;
    #pragma unroll
    for (int i = 0; i < 12; ++i) zp[i] = allred64(zp[i]);

    float a[12];
    #pragma unroll
    for (int i = 0; i < 12; ++i) a[i] = fmaxf(zp[i], 0.f);

    // y partial over this wave's 12 inner dims; b2 only in wave0's partial
    float yp = (w == 0) ? b2o : 0.f;
    #pragma unroll
    for (int i = 0; i < 12; ++i) yp = fmaf(a[i], w2c[i], yp);
    ybuf[st & 1][w][lane] = yp;
    __syncthreads();
    float y = ybuf[st & 1][0][lane] + ybuf[st & 1][1][lane];
    float dy = (y - vj) * 0.03125f;   // 2/64

    // prefetch next step's k,v (st=7 harmlessly loads q row twice)
    int p1 = 2 * st + 2; p1 = p1 < 16 ? p1 : 16;
    int p2 = 2 * st + 3; p2 = p2 < 16 ? p2 : 16;
    int tk2 = __shfl(tok, p1), tv2 = __shfl(tok, p2);
    float kn = etab[tk2 * 64 + lane];
    float vn = etab[tv2 * 64 + lane];

    // backward: dz_i = (z_i>0) * allred(w2[i][c]*dy_c)
    float dz[12];
    #pragma unroll
    for (int i = 0; i < 12; ++i) dz[i] = w2c[i] * dy;
    #pragma unroll
    for (int i = 0; i < 12; ++i) dz[i] = allred64(dz[i]);
    #pragma unroll
    for (int i = 0; i < 12; ++i) dz[i] = (a[i] > 0.f) ? dz[i] : 0.f;

    // Adam step st+1
    pb1 *= 0.9f; pb2 *= 0.999f;
    float cm = 0.05f / (1.f - pb1);
    float sb = 1.f / sqrtf(1.f - pb2);
    #pragma unroll
    for (int i = 0; i < 12; ++i) adam_upd(w1r[i], m1[i], v1[i], kj * dz[i], cm, sb);
    #pragma unroll
    for (int i = 0; i < 12; ++i) adam_upd(w2c[i], m2[i], v2[i], a[i] * dy, cm, sb);
    adam_upd(b2o, mb2, vb2, dy, cm, sb);       // wave1's copy never read
    float gb1 = 0.f;
    #pragma unroll
    for (int i = 0; i < 12; ++i) gb1 = (lane == i) ? dz[i] : gb1;
    adam_upd(b1o, mb1, vb1, gb1, cm, sb);      // lanes>=12: g=0 -> no-op

    kj = kn; vj = vn;
  }

  // final forward with q (kj holds q row after last prefetch)
  float zq[12];
  #pragma unroll
  for (int i = 0; i < 12; ++i) zq[i] = kj * w1r[i];
  #pragma unroll
  for (int i = 0; i < 12; ++i) zq[i] += (lane == i) ? b1o : 0.f;
  #pragma unroll
  for (int i = 0; i < 12; ++i) zq[i] = allred64(zq[i]);
  float hp = (w == 0) ? b2o : 0.f;
  #pragma unroll
  for (int i = 0; i < 12; ++i) hp = fmaf(fmaxf(zq[i], 0.f), w2c[i], hp);

  ybuf[0][w][lane] = hp;
  __syncthreads();
  hqv[lane] = ybuf[0][0][lane] + ybuf[0][1][lane];  // both waves, same bits
  __syncthreads();

  if (w == 0) {
    // out[s][c] = sum_j hq[j] * out_w[j][c] + out_b[c]   (lane = c)
    float acc = out_b[lane];
    const f32x4* hv = (const f32x4*)hqv;
    #pragma unroll
    for (int j4 = 0; j4 < 16; ++j4) {
      f32x4 h4 = hv[j4];
      acc = fmaf(h4.x, out_w[(4 * j4 + 0) * 64 + lane], acc);
      acc = fmaf(h4.y, out_w[(4 * j4 + 1) * 64 + lane], acc);
      acc = fmaf(h4.z, out_w[(4 * j4 + 2) * 64 + lane], acc);
      acc = fmaf(h4.w, out_w[(4 * j4 + 3) * 64 + lane], acc);
    }
    out[(size_t)s * 64 + lane] = acc;
  }
}

extern "C" void kernel_launch(void* const* d_in, const int* in_sizes, int n_in,
                              void* d_out, int out_size, void* d_ws, size_t ws_size,
                              hipStream_t stream) {
  const int*   seqs   = (const int*)d_in[0];
  const float* embed  = (const float*)d_in[1];
  const float* ff_w1  = (const float*)d_in[2];
  const float* ff_b1  = (const float*)d_in[3];
  const float* ff_w2  = (const float*)d_in[4];
  const float* ff_b2  = (const float*)d_in[5];
  const float* ln_g   = (const float*)d_in[6];
  const float* ln_b   = (const float*)d_in[7];
  const float* mlp_w1 = (const float*)d_in[8];
  const float* mlp_b1 = (const float*)d_in[9];
  const float* mlp_w2 = (const float*)d_in[10];
  const float* mlp_b2 = (const float*)d_in[11];
  const float* out_w  = (const float*)d_in[12];
  const float* out_b  = (const float*)d_in[13];

  float* etab = (float*)d_ws;   // 64*64 f32 = 16 KB

  build_table<<<64, 128, 0, stream>>>(
      embed, ff_w1, ff_b1, ff_w2, ff_b2, ln_g, ln_b, etab);
  adapt_kernel<<<BATCHN, 128, 0, stream>>>(
      seqs, etab, mlp_w1, mlp_b1, mlp_w2, mlp_b2, out_w, out_b,
      (float*)d_out);
}

// Round 9
// 207.775 us; speedup vs baseline: 2.9415x; 1.1077x over previous
//
#include <hip/hip_runtime.h>
#include <hip/hip_bf16.h>
#include <math.h>

// Problem constants
#define HID   64
#define VOCABN 64
#define INNER 24
#define SEQN  32
#define CAPN  8
#define NPOS  17
#define BATCHN 8192

typedef float f32x4 __attribute__((ext_vector_type(4)));

// Per-step Adam prefactor, computed at double precision offline:
//   cmsbr[t] = LR * sqrt(1 - B2^(t+1)) / (1 - B1^(t+1)),  t = 0..7
// Replaces runtime sqrtf+div libcalls AND merges bc1/bc2 into one constant.
static __device__ const float CMSBR[8] = {
  0.01581139f, 0.01176584f, 0.01010053f, 0.00918844f,
  0.00862495f, 0.00825540f, 0.00800653f, 0.00783856f
};

// ---------- cross-lane all-reduce, xor-butterfly (bit-exact lineage r4-r8) ----------
__device__ __forceinline__ float allred64(float x) {
  int y;
  y = __builtin_amdgcn_update_dpp(__float_as_int(x), __float_as_int(x),
                                  0xB1, 0xF, 0xF, false);   // quad_perm xor1
  x += __int_as_float(y);
  y = __builtin_amdgcn_update_dpp(__float_as_int(x), __float_as_int(x),
                                  0x4E, 0xF, 0xF, false);   // quad_perm xor2
  x += __int_as_float(y);
  x += __int_as_float(__builtin_amdgcn_ds_swizzle(__float_as_int(x), 0x101F)); // xor4
  x += __int_as_float(__builtin_amdgcn_ds_swizzle(__float_as_int(x), 0x201F)); // xor8
  x += __int_as_float(__builtin_amdgcn_ds_swizzle(__float_as_int(x), 0x401F)); // xor16
  x += __shfl_xor(x, 32);
  return x;
}

// ---------- Kernel 1: per-token encoder table (verbatim round 6, passing) ----------
__global__ __launch_bounds__(128) void build_table(
    const float* __restrict__ embed,    // [64][64]
    const float* __restrict__ ff_w1,    // [64][128]
    const float* __restrict__ ff_b1,    // [128]
    const float* __restrict__ ff_w2,    // [128][64]
    const float* __restrict__ ff_b2,    // [64]
    const float* __restrict__ ln_g,     // [64]
    const float* __restrict__ ln_b,     // [64]
    float* __restrict__ etab)           // [64][64]
{
  __shared__ float h[64];
  __shared__ float A1[128];
  __shared__ float xs[64];
  const int r = blockIdx.x;
  const int t = threadIdx.x;

  if (t < 64) h[t] = embed[r * 64 + t];
  __syncthreads();

  {
    float acc = ff_b1[t];
    #pragma unroll 8
    for (int k = 0; k < 64; ++k)
      acc = fmaf(h[k], ff_w1[k * 128 + t], acc);
    A1[t] = fmaxf(acc, 0.f);
  }
  __syncthreads();

  if (t < 64) {
    float acc = ff_b2[t];
    #pragma unroll 8
    for (int k = 0; k < 128; ++k)
      acc = fmaf(A1[k], ff_w2[k * 64 + t], acc);
    xs[t] = acc + h[t];
  }
  __syncthreads();

  if (t < 64) {
    float s1 = 0.f;
    if (t < 4)
      for (int j = 0; j < 16; ++j) s1 += xs[t + 4 * j];
    s1 += __shfl_xor(s1, 1);
    s1 += __shfl_xor(s1, 2);
    s1 = __shfl(s1, 0);
    float mu = s1 * 0.015625f;

    float s2 = 0.f;
    if (t < 4)
      for (int j = 0; j < 16; ++j) {
        float d = xs[t + 4 * j] - mu;
        s2 = fmaf(d, d, s2);
      }
    s2 += __shfl_xor(s2, 1);
    s2 += __shfl_xor(s2, 2);
    s2 = __shfl(s2, 0);
    float var = s2 * 0.015625f;
    float rs  = rsqrtf(var + 1e-5f);

    etab[r * 64 + t] = fmaf((xs[t] - mu) * rs, ln_g[t], ln_b[t]);
  }
}

// ---------- Kernel 2: 2-wave-per-sample 8-step Adam ----------
// Adam algebra: p -= LR*(m/bc1)/(sqrt(v/bc2)+eps)
//             ~= p - cmsbr * m * rsq(max(v,1e-30))
// (eps dropped: relative deviation ~eps/sqrt(v/bc2), absolute deviation
//  negligible; v=0 => m=0 => delta exactly 0 via the max-guard.)
// g1 = 0.1*g and g2 = 0.001*g^2 arrive pre-scaled by per-step prefactors.
__device__ __forceinline__ void adam_upd(float& p, float& m, float& v,
                                         float g1, float g2, float cmsbr) {
  m = fmaf(0.9f, m, g1);
  v = fmaf(0.999f, v, g2);
  p = fmaf(-(m * cmsbr), __builtin_amdgcn_rsqf(fmaxf(v, 1e-30f)), p);
}

__global__ __launch_bounds__(128, 3) void adapt_kernel(
    const int* __restrict__ seqs,       // [BATCH][32]
    const float* __restrict__ etab,     // [64][64]
    const float* __restrict__ mlp_w1,   // [64][24]
    const float* __restrict__ mlp_b1,   // [24]
    const float* __restrict__ mlp_w2,   // [24][64]
    const float* __restrict__ mlp_b2,   // [64]
    const float* __restrict__ out_w,    // [64][64]
    const float* __restrict__ out_b,    // [64]
    float* __restrict__ out)            // [BATCH][64]
{
  __shared__ float ybuf[2][2][64];     // [step parity][wave][col]
  __shared__ float hqv[64];
  const int t    = threadIdx.x;        // 0..127
  const int lane = t & 63;
  const int w    = t >> 6;             // 0 or 1
  const int s    = blockIdx.x;
  const int i0   = 12 * w;

  int tok = (lane < NPOS) ? seqs[s * SEQN + 14 + lane] : 0;

  // state: lane j owns w1[j][i0..i0+12), w2[i0..i0+12)[j];
  // lanes<12 own b1[i0+lane]; wave0 owns b2[lane].
  float w1r[12], m1[12], v1[12], w2c[12], m2[12], v2[12];
  #pragma unroll
  for (int i = 0; i < 12; ++i) {
    w1r[i] = mlp_w1[lane * 24 + i0 + i];
    w2c[i] = mlp_w2[(i0 + i) * 64 + lane];
    m1[i] = 0.f; v1[i] = 0.f; m2[i] = 0.f; v2[i] = 0.f;
  }
  float b1o = (lane < 12) ? mlp_b1[i0 + lane] : 0.f;
  float b2o = (w == 0) ? mlp_b2[lane] : 0.f;
  float mb1 = 0.f, vb1 = 0.f, mb2 = 0.f, vb2 = 0.f;

  // first k,v rows (direct from L2-resident etab)
  int tk = __shfl(tok, 0), tv = __shfl(tok, 1);
  float kj = etab[tk * 64 + lane];
  float vj = etab[tv * 64 + lane];

  #pragma unroll 1
  for (int st = 0; st < 8; ++st) {
    const float cmsbr = CMSBR[st];

    // forward: z_i (i in wave's half) = allred(k_j * w1[j][i]) + b1
    float zp[12];
    #pragma unroll
    for (int i = 0; i < 12; ++i) zp[i] = kj * w1r[i];
    #pragma unroll
    for (int i = 0; i < 12; ++i) zp[i] += (lane == i) ? b1o : 0.f;
    #pragma unroll
    for (int i = 0; i < 12; ++i) zp[i] = allred64(zp[i]);

    float a[12];
    #pragma unroll
    for (int i = 0; i < 12; ++i) a[i] = fmaxf(zp[i], 0.f);

    // y partial over this wave's 12 inner dims; b2 only in wave0's partial
    float yp = (w == 0) ? b2o : 0.f;
    #pragma unroll
    for (int i = 0; i < 12; ++i) yp = fmaf(a[i], w2c[i], yp);
    ybuf[st & 1][w][lane] = yp;
    __syncthreads();
    float y = ybuf[st & 1][0][lane] + ybuf[st & 1][1][lane];
    float dy = (y - vj) * 0.03125f;   // 2/64

    // prefetch next step's k,v (st=7 harmlessly loads q row twice)
    int p1 = 2 * st + 2; p1 = p1 < 16 ? p1 : 16;
    int p2 = 2 * st + 3; p2 = p2 < 16 ? p2 : 16;
    int tk2 = __shfl(tok, p1), tv2 = __shfl(tok, p2);
    float kn = etab[tk2 * 64 + lane];
    float vn = etab[tv2 * 64 + lane];

    // backward: dz_i = (z_i>0) * allred(w2[i][c]*dy_c)
    float dz[12];
    #pragma unroll
    for (int i = 0; i < 12; ++i) dz[i] = w2c[i] * dy;
    #pragma unroll
    for (int i = 0; i < 12; ++i) dz[i] = allred64(dz[i]);
    #pragma unroll
    for (int i = 0; i < 12; ++i) dz[i] = (a[i] > 0.f) ? dz[i] : 0.f;

    // Adam step st+1; gradient prefactors folded per step
    float kj01 = 0.1f   * kj;
    float kjsq = 0.001f * kj * kj;
    float dy01 = 0.1f   * dy;
    float dysq = 0.001f * dy * dy;
    #pragma unroll
    for (int i = 0; i < 12; ++i)
      adam_upd(w1r[i], m1[i], v1[i], kj01 * dz[i], kjsq * (dz[i] * dz[i]), cmsbr);
    #pragma unroll
    for (int i = 0; i < 12; ++i)
      adam_upd(w2c[i], m2[i], v2[i], dy01 * a[i], dysq * (a[i] * a[i]), cmsbr);
    adam_upd(b2o, mb2, vb2, dy01, dysq, cmsbr);      // wave1's copy never read
    float gb1 = 0.f;
    #pragma unroll
    for (int i = 0; i < 12; ++i) gb1 = (lane == i) ? dz[i] : gb1;
    adam_upd(b1o, mb1, vb1, 0.1f * gb1, 0.001f * (gb1 * gb1), cmsbr);

    kj = kn; vj = vn;
  }

  // final forward with q (kj holds q row after last prefetch)
  float zq[12];
  #pragma unroll
  for (int i = 0; i < 12; ++i) zq[i] = kj * w1r[i];
  #pragma unroll
  for (int i = 0; i < 12; ++i) zq[i] += (lane == i) ? b1o : 0.f;
  #pragma unroll
  for (int i = 0; i < 12; ++i) zq[i] = allred64(zq[i]);
  float hp = (w == 0) ? b2o : 0.f;
  #pragma unroll
  for (int i = 0; i < 12; ++i) hp = fmaf(fmaxf(zq[i], 0.f), w2c[i], hp);

  ybuf[0][w][lane] = hp;
  __syncthreads();
  hqv[lane] = ybuf[0][0][lane] + ybuf[0][1][lane];  // both waves, same bits
  __syncthreads();

  if (w == 0) {
    // out[s][c] = sum_j hq[j] * out_w[j][c] + out_b[c]   (lane = c)
    float acc = out_b[lane];
    const f32x4* hv = (const f32x4*)hqv;
    #pragma unroll
    for (int j4 = 0; j4 < 16; ++j4) {
      f32x4 h4 = hv[j4];
      acc = fmaf(h4.x, out_w[(4 * j4 + 0) * 64 + lane], acc);
      acc = fmaf(h4.y, out_w[(4 * j4 + 1) * 64 + lane], acc);
      acc = fmaf(h4.z, out_w[(4 * j4 + 2) * 64 + lane], acc);
      acc = fmaf(h4.w, out_w[(4 * j4 + 3) * 64 + lane], acc);
    }
    out[(size_t)s * 64 + lane] = acc;
  }
}

extern "C" void kernel_launch(void* const* d_in, const int* in_sizes, int n_in,
                              void* d_out, int out_size, void* d_ws, size_t ws_size,
                              hipStream_t stream) {
  const int*   seqs   = (const int*)d_in[0];
  const float* embed  = (const float*)d_in[1];
  const float* ff_w1  = (const float*)d_in[2];
  const float* ff_b1  = (const float*)d_in[3];
  const float* ff_w2  = (const float*)d_in[4];
  const float* ff_b2  = (const float*)d_in[5];
  const float* ln_g   = (const float*)d_in[6];
  const float* ln_b   = (const float*)d_in[7];
  const float* mlp_w1 = (const float*)d_in[8];
  const float* mlp_b1 = (const float*)d_in[9];
  const float* mlp_w2 = (const float*)d_in[10];
  const float* mlp_b2 = (const float*)d_in[11];
  const float* out_w  = (const float*)d_in[12];
  const float* out_b  = (const float*)d_in[13];

  float* etab = (float*)d_ws;   // 64*64 f32 = 16 KB

  build_table<<<64, 128, 0, stream>>>(
      embed, ff_w1, ff_b1, ff_w2, ff_b2, ln_g, ln_b, etab);
  adapt_kernel<<<BATCHN, 128, 0, stream>>>(
      seqs, etab, mlp_w1, mlp_b1, mlp_w2, mlp_b2, out_w, out_b,
      (float*)d_out);
}